// Round 4
// baseline (561.612 us; speedup 1.0000x reference)
//
#include <hip/hip_runtime.h>

#define NN 16000   // nodes
#define NE 64000   // edges
#define HD 90      // hidden
#define NG 512     // graphs

typedef float f32x4 __attribute__((ext_vector_type(4)));
typedef short s16x8 __attribute__((ext_vector_type(8)));

// round-half-up f32 -> bf16
__device__ __forceinline__ unsigned short rhu1(float f) {
  return (unsigned short)((__builtin_bit_cast(unsigned int, f) + 0x8000u) >> 16);
}
// pack two f32 -> bf16x2 (lo in low half), RHU rounding
__device__ __forceinline__ unsigned int rhu_pack(float lo, float hi) {
  unsigned int ul = __builtin_bit_cast(unsigned int, lo) + 0x8000u;
  unsigned int uh = __builtin_bit_cast(unsigned int, hi) + 0x8000u;
  return __builtin_amdgcn_perm(uh, ul, 0x07060302u);
}
__device__ __forceinline__ float bfhi(unsigned int u) {
  return __builtin_bit_cast(float, u & 0xFFFF0000u);
}
__device__ __forceinline__ float bflo(unsigned int u) {
  return __builtin_bit_cast(float, u << 16);
}

// h0 = concat(x, pos) : [NN, 16]
__global__ void concat_kernel(const float* __restrict__ x, const float* __restrict__ pos,
                              float* __restrict__ h0) {
  int idx = blockIdx.x * 256 + threadIdx.x;
  if (idx >= NN * 16) return;
  int n = idx >> 4, c = idx & 15;
  h0[idx] = (c < 13) ? x[n * 13 + c] : pos[n * 3 + (c - 13)];
}

// he_bf[e][k] : [NE, 96] bf16. k<90: relu(edge MLP); k==90: 1.0 (bias row); k>90: 0
__global__ void edge_mlp_bf(const float* __restrict__ ea, const float* __restrict__ w1,
                            const float* __restrict__ b1, unsigned short* __restrict__ he) {
  int idx = blockIdx.x * 256 + threadIdx.x;
  if (idx >= NE * 96) return;
  int e = idx / 96, k = idx - e * 96;
  unsigned short v;
  if (k < 90) {
    const float* a = ea + e * 8;
    float acc = b1[k];
#pragma unroll
    for (int j = 0; j < 8; j++) acc = fmaf(a[j], w1[j * HD + k], acc);
    v = rhu1(fmaxf(acc, 0.f));
  } else {
    v = (k == 90) ? (unsigned short)0x3F80 : (unsigned short)0;  // bf16(1.0) / 0
  }
  he[idx] = v;
}

// W' prep in MFMA-B-fragment order: shorts laid out as
//   [i][tile t(NTT)][chunk c(3)][lane(64)][j(8)]
// value(i,t,c,lane,j): hk=c*32+(lane>>4)*8+j, o=t*16+(lane&15);
//   hk<90 -> w2[hk][i*OC+o]; hk==90 -> b2[i*OC+o]; else 0.   One block per (i,c).
template <int OC, int NTT>
__global__ void wprep_frag(const float* __restrict__ w2, const float* __restrict__ b2,
                           unsigned short* __restrict__ wout, int inc_oc) {
  const int i = blockIdx.x / 3, c = blockIdx.x - 3 * (blockIdx.x / 3);
  __shared__ float t_s[32 * 100];
  const int tid = threadIdx.x;
  for (int idx = tid; idx < 32 * 96; idx += 256) {
    int kk = idx / 96, o = idx - kk * 96;
    int hk = c * 32 + kk;
    float v = 0.f;
    if (o < OC) {
      if (hk < 90) v = w2[hk * inc_oc + i * OC + o];        // coalesced along o
      else if (hk == 90) v = b2[i * OC + o];
    }
    t_s[kk * 100 + o] = v;
  }
  __syncthreads();
  unsigned int* wo = (unsigned int*)(wout + (size_t)i * NTT * 3 * 512) + c * 256;
  for (int idx = tid; idx < NTT * 256; idx += 256) {
    int t = idx >> 8, r = idx & 255;
    int lane = r >> 2, u = r & 3;
    int kk = (lane >> 4) * 8 + 2 * u;
    int o = t * 16 + (lane & 15);
    wo[(size_t)t * 3 * 256 + lane * 4 + u] = rhu_pack(t_s[kk * 100 + o], t_s[(kk + 1) * 100 + o]);
  }
}

// Fused message GEMM + scatter, LDS-staged W' (R3) + MT m-tiles/wave (R4).
// R3 counters closed the model: LDS-read was the top pipe (164KB/CU-iter
// ~ 1930cyc = 53% of wall) because each W' fragment read fed only 2 MFMAs
// (MT=2). R4: MT=4 -> each 16B/lane B-fragment feeds 4 MFMAs; per-CU-iter
// LDS reads drop 164->90KB, MFMA (1397cyc/SIMD) becomes the top pipe.
// Fewer, fatter waves: VGPR ~170-190 (af 48 + acc 48 + ba 36 + zv 16),
// launch_bounds(BLK,2); occupancy ~25% is intended (LDS caps 2 blocks/CU).
// Per i (per wave): issue stage(i+1) [global_load_lds w=16, no wait] ->
// ds_read z (MT/2 b128) + 9 b128 W' frags -> 9*MT MFMA + 12*MT VALU fma ->
// __syncthreads (drains own vmcnt; barrier => buf[i+1] complete).
template <int ILIM, int OC, int NTT, int NWG, int MT, int EPB, int BLK>
__global__ __launch_bounds__(BLK, 2)
void msg_mfma(const unsigned short* __restrict__ he,
              const float* __restrict__ nin,
              const int* __restrict__ src, const int* __restrict__ dst,
              const unsigned short* __restrict__ wp,
              float* __restrict__ agg) {
  constexpr int WMG = EPB / 32;          // 32-edge z-groups per block
  constexpr int TPE = BLK / EPB;
  constexpr int NWAVES = BLK / 64;       // = (EPB/(16*MT)) * NWG
  constexpr int NF = NTT * 3;            // 1KB fragments per i (whole W'[i])
  constexpr int MG = MT / 2;             // z-groups per wave
  __shared__ unsigned short zb[ILIM * WMG * 32];   // [i][grp][q][8] bf16, quad-permuted
  __shared__ unsigned short wbuf[2][NF * 512];     // W'[i] double buffer
  __shared__ int dst_s[EPB];
  const int tid = threadIdx.x;
  const int e0 = blockIdx.x * EPB;
  const int wid = tid >> 6, l = tid & 63, ln = tid & 15, q = (tid & 63) >> 4;
  const int wn = wid % NWG, wm = wid / NWG;
  const int eb = wm * MT * 16;
  const int wn3 = wn * 3;

  // stage W'[ii] -> wbuf[buf]: NF fragments of 1KB, distributed over waves.
  // LDS dest is wave-uniform base (HW adds lane*16); global src is per-lane.
  const unsigned short* wl = wp + l * 8;
  auto stage = [&](const unsigned short* wb, int buf) {
#pragma unroll
    for (int t = 0; t < (NF + NWAVES - 1) / NWAVES; t++) {
      const int s = wid + t * NWAVES;
      if (s < NF) {
        __builtin_amdgcn_global_load_lds(
            (const __attribute__((address_space(1))) unsigned int*)(wb + (size_t)s * 512),
            (__attribute__((address_space(3))) unsigned int*)&wbuf[buf][s * 512],
            16, 0, 0);
      }
    }
  };

  stage(wl, 0);   // prefetch W'[0] while we stage z / load af
  const unsigned short* wnext = wl + (size_t)NF * 512;   // W'[1] base (per-lane)

  if (tid < EPB) dst_s[tid] = dst[e0 + tid];

  // stage z (bf16) into quad-permuted layout:
  //   slot(e,i) = (i*WMG + (e>>5))*32 + ((e&15)>>2)*8 + ((e>>4)&1)*4 + (e&3)
  {
    const int e = tid % EPB, jj = tid / EPB;
    const int base = (e >> 5) * 32 + (((e & 15) >> 2) << 3) + (((e >> 4) & 1) << 2) + (e & 3);
    const float* zr = nin + (size_t)src[e0 + e] * ILIM;
    for (int p = jj; p < ILIM / 2; p += TPE) {
      const float2 v = *(const float2*)(zr + 2 * p);
      zb[(2 * p) * (WMG * 32) + base] = rhu1(v.x);
      zb[(2 * p + 1) * (WMG * 32) + base] = rhu1(v.y);
    }
  }

  // A-fragments: raw bf16 he, register-resident for the whole kernel
  s16x8 af[MT][3];
#pragma unroll
  for (int mt = 0; mt < MT; mt++) {
    const unsigned short* hr = he + (size_t)(e0 + eb + mt * 16 + ln) * 96 + q * 8;
#pragma unroll
    for (int c = 0; c < 3; c++) af[mt][c] = *(const s16x8*)(hr + c * 32);
  }

  __syncthreads();   // zb/dst_s ready AND wbuf[0] staged (vmcnt drained)

  f32x4 acc[MT][3];
#pragma unroll
  for (int mt = 0; mt < MT; mt++)
#pragma unroll
    for (int nt = 0; nt < 3; nt++) acc[mt][nt] = (f32x4)0.f;

#pragma clang loop unroll(disable)
  for (int i = 0; i < ILIM; i++) {
    const int cur = i & 1;
    // issue next-i staging first: loads fly under this iter's ds_read+MFMA
    if (i + 1 < ILIM) { stage(wnext, cur ^ 1); wnext += (size_t)NF * 512; }

    // z for this i: MG b128 broadcast reads -> 8 bf16 each (2 m-tiles apiece)
    f32x4 zv[MT];
#pragma unroll
    for (int g = 0; g < MG; g++) {
      const uint4 zu = *(const uint4*)&zb[(i * WMG + wm * MG + g) * 32 + q * 8];
      zv[2 * g][0] = bflo(zu.x); zv[2 * g][1] = bfhi(zu.x);
      zv[2 * g][2] = bflo(zu.y); zv[2 * g][3] = bfhi(zu.y);
      zv[2 * g + 1][0] = bflo(zu.z); zv[2 * g + 1][1] = bfhi(zu.z);
      zv[2 * g + 1][2] = bflo(zu.w); zv[2 * g + 1][3] = bfhi(zu.w);
    }

    // W' fragments for this wave's 3 n-tiles from LDS (ds_read_b128 x9)
    uint4 ba[9];
#pragma unroll
    for (int ntl = 0; ntl < 3; ntl++)
#pragma unroll
      for (int c = 0; c < 3; c++)
        ba[ntl * 3 + c] = *(const uint4*)&wbuf[cur][((wn3 + ntl) * 3 + c) * 512 + l * 8];

#pragma unroll
    for (int ntl = 0; ntl < 3; ntl++) {
#pragma unroll
      for (int mt = 0; mt < MT; mt++) {
        f32x4 t = __builtin_amdgcn_mfma_f32_16x16x32_bf16(af[mt][0], __builtin_bit_cast(s16x8, ba[ntl * 3 + 0]), (f32x4)0.f, 0, 0, 0);
        t = __builtin_amdgcn_mfma_f32_16x16x32_bf16(af[mt][1], __builtin_bit_cast(s16x8, ba[ntl * 3 + 1]), t, 0, 0, 0);
        t = __builtin_amdgcn_mfma_f32_16x16x32_bf16(af[mt][2], __builtin_bit_cast(s16x8, ba[ntl * 3 + 2]), t, 0, 0, 0);
        acc[mt][ntl] += zv[mt] * t;
      }
    }

    // barrier: all waves done reading wbuf[cur]; own staging loads drained
    // (compiler emits vmcnt(0) lgkmcnt(0) before s_barrier) => wbuf[cur^1]
    // fully staged for i+1.
    if (i + 1 < ILIM) __syncthreads();
  }

  // epilogue: D[row=q*4+r][col=ln] -> atomicAdd agg[dst]
#pragma unroll
  for (int mt = 0; mt < MT; mt++) {
#pragma unroll
    for (int ntl = 0; ntl < 3; ntl++) {
      int o = wn * 48 + ntl * 16 + ln;
      if (o < OC) {
#pragma unroll
        for (int r = 0; r < 4; r++) {
          int el = eb + mt * 16 + q * 4 + r;
          atomicAdd(agg + (size_t)dst_s[el] * OC + o, acc[mt][ntl][r]);
        }
      }
    }
  }
}

// out[n][o] = relu(agg[n][o] + sum_i nin[n][i]*root[i][o] + bias[o])   (fp32 exact)
template <int IN_C, int OC>
__global__ void node_kernel(const float* __restrict__ agg, const float* __restrict__ nin,
                            const float* __restrict__ root, const float* __restrict__ bias,
                            float* __restrict__ out) {
  int idx = blockIdx.x * 256 + threadIdx.x;
  if (idx >= NN * OC) return;
  int n = idx / OC, o = idx - n * OC;
  float acc = agg[idx] + bias[o];
  const float* inp = nin + (size_t)n * IN_C;
#pragma unroll 6
  for (int i = 0; i < IN_C; i++) acc = fmaf(inp[i], root[i * OC + o], acc);
  out[idx] = fmaxf(acc, 0.f);
}

// per-graph: pool (batch sorted -> binary search) + fc1 + out
__global__ void pool_mlp_kernel(const float* __restrict__ h3, const int* __restrict__ batch,
                                const float* __restrict__ fc1_w, const float* __restrict__ fc1_b,
                                const float* __restrict__ out_w, const float* __restrict__ out_b,
                                float* __restrict__ out) {
  const int b = blockIdx.x;
  const int tid = threadIdx.x;
  __shared__ float g[45];
  __shared__ float go[90];
  __shared__ int rng[2];
  if (tid < 2) {
    int target = b + tid;
    int lo = 0, hi = NN;
    while (lo < hi) { int mid = (lo + hi) >> 1; if (batch[mid] < target) lo = mid + 1; else hi = mid; }
    rng[tid] = lo;
  }
  __syncthreads();
  const int s = rng[0], e = rng[1];
  if (tid < 45) {
    float acc = 0.f;
    for (int n = s; n < e; n++) acc += h3[n * 45 + tid];
    g[tid] = acc;
  }
  __syncthreads();
  if (tid < 90) {
    float acc = fc1_b[tid];
#pragma unroll 5
    for (int i = 0; i < 45; i++) acc = fmaf(g[i], fc1_w[i * 90 + tid], acc);
    go[tid] = fmaxf(acc, 0.f) * out_w[tid];
  }
  __syncthreads();
  if (tid == 0) {
    float acc = out_b[0];
    for (int i = 0; i < 90; i++) acc += go[i];
    out[b] = acc;
  }
}

extern "C" void kernel_launch(void* const* d_in, const int* in_sizes, int n_in,
                              void* d_out, int out_size, void* d_ws, size_t ws_size,
                              hipStream_t stream) {
  const float* x       = (const float*)d_in[0];
  const float* pos     = (const float*)d_in[1];
  const float* ea      = (const float*)d_in[2];
  const int*   eidx    = (const int*)d_in[3];
  const int*   batch   = (const int*)d_in[4];
  const float* c1_w1   = (const float*)d_in[5];
  const float* c1_b1   = (const float*)d_in[6];
  const float* c1_w2   = (const float*)d_in[7];
  const float* c1_b2   = (const float*)d_in[8];
  const float* c1_root = (const float*)d_in[9];
  const float* c1_bias = (const float*)d_in[10];
  const float* c2_w1   = (const float*)d_in[11];
  const float* c2_b1   = (const float*)d_in[12];
  const float* c2_w2   = (const float*)d_in[13];
  const float* c2_b2   = (const float*)d_in[14];
  const float* c2_root = (const float*)d_in[15];
  const float* c2_bias = (const float*)d_in[16];
  const float* c3_w1   = (const float*)d_in[17];
  const float* c3_b1   = (const float*)d_in[18];
  const float* c3_w2   = (const float*)d_in[19];
  const float* c3_b2   = (const float*)d_in[20];
  const float* c3_root = (const float*)d_in[21];
  const float* c3_bias = (const float*)d_in[22];
  const float* fc1_w   = (const float*)d_in[23];
  const float* fc1_b   = (const float*)d_in[24];
  const float* out_w   = (const float*)d_in[25];
  const float* out_b   = (const float*)d_in[26];
  const int* src = eidx;
  const int* dst = eidx + NE;

  // workspace carve
  float* ws  = (float*)d_ws;
  float* h0  = ws;                       // NN*16
  float* h1  = h0 + NN * 16;             // NN*90
  float* h2  = h1 + NN * 90;             // NN*90
  float* h3  = h2 + NN * 90;             // NN*45
  float* agg = h3 + NN * 45;             // NN*90
  unsigned short* he_bf = (unsigned short*)(agg + NN * 90);   // NE*96
  unsigned short* wp1 = he_bf + (size_t)NE * 96;              // 16*6*3*512
  unsigned short* wp2 = wp1 + (size_t)16 * 6 * 3 * 512;       // 90*6*3*512
  unsigned short* wp3 = wp2 + (size_t)90 * 6 * 3 * 512;       // 90*3*3*512

  concat_kernel<<<(NN * 16) / 256, 256, 0, stream>>>(x, pos, h0);

  wprep_frag<90, 6><<<16 * 3, 256, 0, stream>>>(c1_w2, c1_b2, wp1, 16 * 90);
  wprep_frag<90, 6><<<90 * 3, 256, 0, stream>>>(c2_w2, c2_b2, wp2, 90 * 90);
  wprep_frag<45, 3><<<90 * 3, 256, 0, stream>>>(c3_w2, c3_b2, wp3, 90 * 45);

  // conv1: 16 -> 90   (128 edges/block, 4 waves: 2 wm(4 m-tiles) x 2 wn)
  hipMemsetAsync(agg, 0, (size_t)NN * 90 * sizeof(float), stream);
  edge_mlp_bf<<<(NE * 96) / 256, 256, 0, stream>>>(ea, c1_w1, c1_b1, he_bf);
  msg_mfma<16, 90, 6, 2, 4, 128, 256><<<NE / 128, 256, 0, stream>>>(he_bf, h0, src, dst, wp1, agg);
  node_kernel<16, 90><<<(NN * 90) / 256, 256, 0, stream>>>(agg, h0, c1_root, c1_bias, h1);

  // conv2: 90 -> 90   (128 edges/block, 4 waves: 2 wm(4 m-tiles) x 2 wn)
  hipMemsetAsync(agg, 0, (size_t)NN * 90 * sizeof(float), stream);
  edge_mlp_bf<<<(NE * 96) / 256, 256, 0, stream>>>(ea, c2_w1, c2_b1, he_bf);
  msg_mfma<90, 90, 6, 2, 4, 128, 256><<<NE / 128, 256, 0, stream>>>(he_bf, h1, src, dst, wp2, agg);
  node_kernel<90, 90><<<(NN * 90) / 256, 256, 0, stream>>>(agg, h1, c2_root, c2_bias, h2);

  // conv3: 90 -> 45   (128 edges/block, 2 waves: 2 wm(4 m-tiles) x 1 wn)
  hipMemsetAsync(agg, 0, (size_t)NN * 45 * sizeof(float), stream);
  edge_mlp_bf<<<(NE * 96) / 256, 256, 0, stream>>>(ea, c3_w1, c3_b1, he_bf);
  msg_mfma<90, 45, 3, 1, 4, 128, 128><<<NE / 128, 128, 0, stream>>>(he_bf, h2, src, dst, wp3, agg);
  node_kernel<90, 45><<<(NN * 45 + 255) / 256, 256, 0, stream>>>(agg, h2, c3_root, c3_bias, h3);

  pool_mlp_kernel<<<NG, 128, 0, stream>>>(h3, batch, fc1_w, fc1_b, out_w, out_b, (float*)d_out);
}

// Round 5
// 541.927 us; speedup vs baseline: 1.0363x; 1.0363x over previous
//
#include <hip/hip_runtime.h>

#define NN 16000   // nodes
#define NE 64000   // edges
#define HD 90      // hidden
#define NG 512     // graphs

typedef float f32x4 __attribute__((ext_vector_type(4)));
typedef short s16x8 __attribute__((ext_vector_type(8)));

// round-half-up f32 -> bf16
__device__ __forceinline__ unsigned short rhu1(float f) {
  return (unsigned short)((__builtin_bit_cast(unsigned int, f) + 0x8000u) >> 16);
}
// pack two f32 -> bf16x2 (lo in low half), RHU rounding
__device__ __forceinline__ unsigned int rhu_pack(float lo, float hi) {
  unsigned int ul = __builtin_bit_cast(unsigned int, lo) + 0x8000u;
  unsigned int uh = __builtin_bit_cast(unsigned int, hi) + 0x8000u;
  return __builtin_amdgcn_perm(uh, ul, 0x07060302u);
}
__device__ __forceinline__ float bfhi(unsigned int u) {
  return __builtin_bit_cast(float, u & 0xFFFF0000u);
}
__device__ __forceinline__ float bflo(unsigned int u) {
  return __builtin_bit_cast(float, u << 16);
}

// h0 = concat(x, pos) : [NN, 16]
__global__ void concat_kernel(const float* __restrict__ x, const float* __restrict__ pos,
                              float* __restrict__ h0) {
  int idx = blockIdx.x * 256 + threadIdx.x;
  if (idx >= NN * 16) return;
  int n = idx >> 4, c = idx & 15;
  h0[idx] = (c < 13) ? x[n * 13 + c] : pos[n * 3 + (c - 13)];
}

// he_bf[e][k] : [NE, 96] bf16. k<90: relu(edge MLP); k==90: 1.0 (bias row); k>90: 0
__global__ void edge_mlp_bf(const float* __restrict__ ea, const float* __restrict__ w1,
                            const float* __restrict__ b1, unsigned short* __restrict__ he) {
  int idx = blockIdx.x * 256 + threadIdx.x;
  if (idx >= NE * 96) return;
  int e = idx / 96, k = idx - e * 96;
  unsigned short v;
  if (k < 90) {
    const float* a = ea + e * 8;
    float acc = b1[k];
#pragma unroll
    for (int j = 0; j < 8; j++) acc = fmaf(a[j], w1[j * HD + k], acc);
    v = rhu1(fmaxf(acc, 0.f));
  } else {
    v = (k == 90) ? (unsigned short)0x3F80 : (unsigned short)0;  // bf16(1.0) / 0
  }
  he[idx] = v;
}

// W' prep in MFMA-B-fragment order: shorts laid out as
//   [i][tile t(NTT)][chunk c(3)][lane(64)][j(8)]
// value(i,t,c,lane,j): hk=c*32+(lane>>4)*8+j, o=t*16+(lane&15);
//   hk<90 -> w2[hk][i*OC+o]; hk==90 -> b2[i*OC+o]; else 0.   One block per (i,c).
template <int OC, int NTT>
__global__ void wprep_frag(const float* __restrict__ w2, const float* __restrict__ b2,
                           unsigned short* __restrict__ wout, int inc_oc) {
  const int i = blockIdx.x / 3, c = blockIdx.x - 3 * (blockIdx.x / 3);
  __shared__ float t_s[32 * 100];
  const int tid = threadIdx.x;
  for (int idx = tid; idx < 32 * 96; idx += 256) {
    int kk = idx / 96, o = idx - kk * 96;
    int hk = c * 32 + kk;
    float v = 0.f;
    if (o < OC) {
      if (hk < 90) v = w2[hk * inc_oc + i * OC + o];        // coalesced along o
      else if (hk == 90) v = b2[i * OC + o];
    }
    t_s[kk * 100 + o] = v;
  }
  __syncthreads();
  unsigned int* wo = (unsigned int*)(wout + (size_t)i * NTT * 3 * 512) + c * 256;
  for (int idx = tid; idx < NTT * 256; idx += 256) {
    int t = idx >> 8, r = idx & 255;
    int lane = r >> 2, u = r & 3;
    int kk = (lane >> 4) * 8 + 2 * u;
    int o = t * 16 + (lane & 15);
    wo[(size_t)t * 3 * 256 + lane * 4 + u] = rhu_pack(t_s[kk * 100 + o], t_s[(kk + 1) * 100 + o]);
  }
}

// Fused message GEMM + scatter, LDS-staged W' (R3) + MT=4 m-tiles/wave (R4).
// Round-12 change: the W' double buffer is now TWO DISTINCT __shared__
// objects (wbA/wbB) and the i-loop is unrolled by 2 with literal buffer
// names per half. Rationale: with one wbuf[2][...] array and runtime
// cur, LLVM alias analysis cannot prove the global_load_lds writes into
// wbuf[cur^1] don't overlap the ds_read_b128 of wbuf[cur]; it must order
// them, inserting s_waitcnt vmcnt(0) BEFORE the ds_reads — exposing the
// full L2 staging latency at the top of every iteration. That serial
// chain (drain + ds_read burst + MFMA + barrier) is the ~3640cyc/iter
// invariant that R1/R2/R4's pipe-load changes couldn't move (MfmaUtil
// pinned at 33% with MFMA demand only ~1400cyc/SIMD). Distinct objects
// -> AA disambiguates -> stage-issue floats past the reads; the only
// vmcnt(0) is the pre-barrier drain, covered by the ~1400cyc MFMA phase.
// Numerics bit-identical (same bytes, same MFMA sequence).
template <int ILIM, int OC, int NTT, int NWG, int MT, int EPB, int BLK>
__global__ __launch_bounds__(BLK, 2)
void msg_mfma(const unsigned short* __restrict__ he,
              const float* __restrict__ nin,
              const int* __restrict__ src, const int* __restrict__ dst,
              const unsigned short* __restrict__ wp,
              float* __restrict__ agg) {
  constexpr int WMG = EPB / 32;          // 32-edge z-groups per block
  constexpr int TPE = BLK / EPB;
  constexpr int NWAVES = BLK / 64;       // = (EPB/(16*MT)) * NWG
  constexpr int NF = NTT * 3;            // 1KB fragments per i (whole W'[i])
  constexpr int MG = MT / 2;             // z-groups per wave
  __shared__ unsigned short zb[ILIM * WMG * 32];   // [i][grp][q][8] bf16, quad-permuted
  __shared__ unsigned short wbA[NF * 512];         // W' ping buffer (distinct object!)
  __shared__ unsigned short wbB[NF * 512];         // W' pong buffer (distinct object!)
  __shared__ int dst_s[EPB];
  const int tid = threadIdx.x;
  const int e0 = blockIdx.x * EPB;
  const int wid = tid >> 6, l = tid & 63, ln = tid & 15, q = (tid & 63) >> 4;
  const int wn = wid % NWG, wm = wid / NWG;
  const int eb = wm * MT * 16;
  const int wn3 = wn * 3;

  // stage W' slab (NF x 1KB fragments) -> the given LDS buffer, frags
  // distributed over waves. LDS dest is wave-uniform base (+lane*16);
  // global src is per-lane.
  const unsigned short* wl = wp + l * 8;
  auto stage = [&](const unsigned short* wb, unsigned short* lb) {
#pragma unroll
    for (int t = 0; t < (NF + NWAVES - 1) / NWAVES; t++) {
      const int s = wid + t * NWAVES;
      if (s < NF) {
        __builtin_amdgcn_global_load_lds(
            (const __attribute__((address_space(1))) unsigned int*)(wb + (size_t)s * 512),
            (__attribute__((address_space(3))) unsigned int*)(lb + s * 512),
            16, 0, 0);
      }
    }
  };

  // one i-step: z decode + 9 b128 W' reads from lb + 9*MT MFMA + acc FMA
  f32x4 acc[MT][3];
  s16x8 af[MT][3];
  auto compute = [&](int i, const unsigned short* lb) {
    f32x4 zv[MT];
#pragma unroll
    for (int g = 0; g < MG; g++) {
      const uint4 zu = *(const uint4*)&zb[(i * WMG + wm * MG + g) * 32 + q * 8];
      zv[2 * g][0] = bflo(zu.x); zv[2 * g][1] = bfhi(zu.x);
      zv[2 * g][2] = bflo(zu.y); zv[2 * g][3] = bfhi(zu.y);
      zv[2 * g + 1][0] = bflo(zu.z); zv[2 * g + 1][1] = bfhi(zu.z);
      zv[2 * g + 1][2] = bflo(zu.w); zv[2 * g + 1][3] = bfhi(zu.w);
    }
    uint4 ba[9];
#pragma unroll
    for (int ntl = 0; ntl < 3; ntl++)
#pragma unroll
      for (int c = 0; c < 3; c++)
        ba[ntl * 3 + c] = *(const uint4*)(lb + ((wn3 + ntl) * 3 + c) * 512 + l * 8);
#pragma unroll
    for (int ntl = 0; ntl < 3; ntl++) {
#pragma unroll
      for (int mt = 0; mt < MT; mt++) {
        f32x4 t = __builtin_amdgcn_mfma_f32_16x16x32_bf16(af[mt][0], __builtin_bit_cast(s16x8, ba[ntl * 3 + 0]), (f32x4)0.f, 0, 0, 0);
        t = __builtin_amdgcn_mfma_f32_16x16x32_bf16(af[mt][1], __builtin_bit_cast(s16x8, ba[ntl * 3 + 1]), t, 0, 0, 0);
        t = __builtin_amdgcn_mfma_f32_16x16x32_bf16(af[mt][2], __builtin_bit_cast(s16x8, ba[ntl * 3 + 2]), t, 0, 0, 0);
        acc[mt][ntl] += zv[mt] * t;
      }
    }
  };

  stage(wl, wbA);   // prefetch W'[0] while we stage z / load af

  if (tid < EPB) dst_s[tid] = dst[e0 + tid];

  // stage z (bf16) into quad-permuted layout:
  //   slot(e,i) = (i*WMG + (e>>5))*32 + ((e&15)>>2)*8 + ((e>>4)&1)*4 + (e&3)
  {
    const int e = tid % EPB, jj = tid / EPB;
    const int base = (e >> 5) * 32 + (((e & 15) >> 2) << 3) + (((e >> 4) & 1) << 2) + (e & 3);
    const float* zr = nin + (size_t)src[e0 + e] * ILIM;
    for (int p = jj; p < ILIM / 2; p += TPE) {
      const float2 v = *(const float2*)(zr + 2 * p);
      zb[(2 * p) * (WMG * 32) + base] = rhu1(v.x);
      zb[(2 * p + 1) * (WMG * 32) + base] = rhu1(v.y);
    }
  }

  // A-fragments: raw bf16 he, register-resident for the whole kernel
#pragma unroll
  for (int mt = 0; mt < MT; mt++) {
    const unsigned short* hr = he + (size_t)(e0 + eb + mt * 16 + ln) * 96 + q * 8;
#pragma unroll
    for (int c = 0; c < 3; c++) af[mt][c] = *(const s16x8*)(hr + c * 32);
  }

#pragma unroll
  for (int mt = 0; mt < MT; mt++)
#pragma unroll
    for (int nt = 0; nt < 3; nt++) acc[mt][nt] = (f32x4)0.f;

  __syncthreads();   // zb/dst_s ready AND wbA staged (vmcnt drained)

  const unsigned short* wnext = wl + (size_t)NF * 512;   // W'[1] base (per-lane)

#pragma clang loop unroll(disable)
  for (int i = 0; i < ILIM; i += 2) {
    // even half: stage i+1 -> wbB (distinct object: no false dep on wbA
    // reads), compute i from wbA, barrier (drains own stage loads).
    stage(wnext, wbB);
    wnext += (size_t)NF * 512;
    compute(i, wbA);
    __syncthreads();
    // odd half: stage i+2 -> wbA (if it exists), compute i+1 from wbB.
    if (i + 2 < ILIM) {
      stage(wnext, wbA);
      wnext += (size_t)NF * 512;
    }
    compute(i + 1, wbB);
    if (i + 2 < ILIM) __syncthreads();
  }

  // epilogue: D[row=q*4+r][col=ln] -> atomicAdd agg[dst]
#pragma unroll
  for (int mt = 0; mt < MT; mt++) {
#pragma unroll
    for (int ntl = 0; ntl < 3; ntl++) {
      int o = wn * 48 + ntl * 16 + ln;
      if (o < OC) {
#pragma unroll
        for (int r = 0; r < 4; r++) {
          int el = eb + mt * 16 + q * 4 + r;
          atomicAdd(agg + (size_t)dst_s[el] * OC + o, acc[mt][ntl][r]);
        }
      }
    }
  }
}

// out[n][o] = relu(agg[n][o] + sum_i nin[n][i]*root[i][o] + bias[o])   (fp32 exact)
template <int IN_C, int OC>
__global__ void node_kernel(const float* __restrict__ agg, const float* __restrict__ nin,
                            const float* __restrict__ root, const float* __restrict__ bias,
                            float* __restrict__ out) {
  int idx = blockIdx.x * 256 + threadIdx.x;
  if (idx >= NN * OC) return;
  int n = idx / OC, o = idx - n * OC;
  float acc = agg[idx] + bias[o];
  const float* inp = nin + (size_t)n * IN_C;
#pragma unroll 6
  for (int i = 0; i < IN_C; i++) acc = fmaf(inp[i], root[i * OC + o], acc);
  out[idx] = fmaxf(acc, 0.f);
}

// per-graph: pool (batch sorted -> binary search) + fc1 + out
__global__ void pool_mlp_kernel(const float* __restrict__ h3, const int* __restrict__ batch,
                                const float* __restrict__ fc1_w, const float* __restrict__ fc1_b,
                                const float* __restrict__ out_w, const float* __restrict__ out_b,
                                float* __restrict__ out) {
  const int b = blockIdx.x;
  const int tid = threadIdx.x;
  __shared__ float g[45];
  __shared__ float go[90];
  __shared__ int rng[2];
  if (tid < 2) {
    int target = b + tid;
    int lo = 0, hi = NN;
    while (lo < hi) { int mid = (lo + hi) >> 1; if (batch[mid] < target) lo = mid + 1; else hi = mid; }
    rng[tid] = lo;
  }
  __syncthreads();
  const int s = rng[0], e = rng[1];
  if (tid < 45) {
    float acc = 0.f;
    for (int n = s; n < e; n++) acc += h3[n * 45 + tid];
    g[tid] = acc;
  }
  __syncthreads();
  if (tid < 90) {
    float acc = fc1_b[tid];
#pragma unroll 5
    for (int i = 0; i < 45; i++) acc = fmaf(g[i], fc1_w[i * 90 + tid], acc);
    go[tid] = fmaxf(acc, 0.f) * out_w[tid];
  }
  __syncthreads();
  if (tid == 0) {
    float acc = out_b[0];
    for (int i = 0; i < 90; i++) acc += go[i];
    out[b] = acc;
  }
}

extern "C" void kernel_launch(void* const* d_in, const int* in_sizes, int n_in,
                              void* d_out, int out_size, void* d_ws, size_t ws_size,
                              hipStream_t stream) {
  const float* x       = (const float*)d_in[0];
  const float* pos     = (const float*)d_in[1];
  const float* ea      = (const float*)d_in[2];
  const int*   eidx    = (const int*)d_in[3];
  const int*   batch   = (const int*)d_in[4];
  const float* c1_w1   = (const float*)d_in[5];
  const float* c1_b1   = (const float*)d_in[6];
  const float* c1_w2   = (const float*)d_in[7];
  const float* c1_b2   = (const float*)d_in[8];
  const float* c1_root = (const float*)d_in[9];
  const float* c1_bias = (const float*)d_in[10];
  const float* c2_w1   = (const float*)d_in[11];
  const float* c2_b1   = (const float*)d_in[12];
  const float* c2_w2   = (const float*)d_in[13];
  const float* c2_b2   = (const float*)d_in[14];
  const float* c2_root = (const float*)d_in[15];
  const float* c2_bias = (const float*)d_in[16];
  const float* c3_w1   = (const float*)d_in[17];
  const float* c3_b1   = (const float*)d_in[18];
  const float* c3_w2   = (const float*)d_in[19];
  const float* c3_b2   = (const float*)d_in[20];
  const float* c3_root = (const float*)d_in[21];
  const float* c3_bias = (const float*)d_in[22];
  const float* fc1_w   = (const float*)d_in[23];
  const float* fc1_b   = (const float*)d_in[24];
  const float* out_w   = (const float*)d_in[25];
  const float* out_b   = (const float*)d_in[26];
  const int* src = eidx;
  const int* dst = eidx + NE;

  // workspace carve
  float* ws  = (float*)d_ws;
  float* h0  = ws;                       // NN*16
  float* h1  = h0 + NN * 16;             // NN*90
  float* h2  = h1 + NN * 90;             // NN*90
  float* h3  = h2 + NN * 90;             // NN*45
  float* agg = h3 + NN * 45;             // NN*90
  unsigned short* he_bf = (unsigned short*)(agg + NN * 90);   // NE*96
  unsigned short* wp1 = he_bf + (size_t)NE * 96;              // 16*6*3*512
  unsigned short* wp2 = wp1 + (size_t)16 * 6 * 3 * 512;       // 90*6*3*512
  unsigned short* wp3 = wp2 + (size_t)90 * 6 * 3 * 512;       // 90*3*3*512

  concat_kernel<<<(NN * 16) / 256, 256, 0, stream>>>(x, pos, h0);

  wprep_frag<90, 6><<<16 * 3, 256, 0, stream>>>(c1_w2, c1_b2, wp1, 16 * 90);
  wprep_frag<90, 6><<<90 * 3, 256, 0, stream>>>(c2_w2, c2_b2, wp2, 90 * 90);
  wprep_frag<45, 3><<<90 * 3, 256, 0, stream>>>(c3_w2, c3_b2, wp3, 90 * 45);

  // conv1: 16 -> 90   (128 edges/block, 4 waves: 2 wm(4 m-tiles) x 2 wn)
  hipMemsetAsync(agg, 0, (size_t)NN * 90 * sizeof(float), stream);
  edge_mlp_bf<<<(NE * 96) / 256, 256, 0, stream>>>(ea, c1_w1, c1_b1, he_bf);
  msg_mfma<16, 90, 6, 2, 4, 128, 256><<<NE / 128, 256, 0, stream>>>(he_bf, h0, src, dst, wp1, agg);
  node_kernel<16, 90><<<(NN * 90) / 256, 256, 0, stream>>>(agg, h0, c1_root, c1_bias, h1);

  // conv2: 90 -> 90   (128 edges/block, 4 waves: 2 wm(4 m-tiles) x 2 wn)
  hipMemsetAsync(agg, 0, (size_t)NN * 90 * sizeof(float), stream);
  edge_mlp_bf<<<(NE * 96) / 256, 256, 0, stream>>>(ea, c2_w1, c2_b1, he_bf);
  msg_mfma<90, 90, 6, 2, 4, 128, 256><<<NE / 128, 256, 0, stream>>>(he_bf, h1, src, dst, wp2, agg);
  node_kernel<90, 90><<<(NN * 90) / 256, 256, 0, stream>>>(agg, h1, c2_root, c2_bias, h2);

  // conv3: 90 -> 45   (128 edges/block, 2 waves: 2 wm(4 m-tiles) x 1 wn)
  hipMemsetAsync(agg, 0, (size_t)NN * 45 * sizeof(float), stream);
  edge_mlp_bf<<<(NE * 96) / 256, 256, 0, stream>>>(ea, c3_w1, c3_b1, he_bf);
  msg_mfma<90, 45, 3, 1, 4, 128, 128><<<NE / 128, 128, 0, stream>>>(he_bf, h2, src, dst, wp3, agg);
  node_kernel<90, 45><<<(NN * 45 + 255) / 256, 256, 0, stream>>>(agg, h2, c3_root, c3_bias, h3);

  pool_mlp_kernel<<<NG, 128, 0, stream>>>(h3, batch, fc1_w, fc1_b, out_w, out_b, (float*)d_out);
}